// Round 2
// baseline (1062.013 us; speedup 1.0000x reference)
//
#include <hip/hip_runtime.h>

typedef unsigned short u16;
typedef float f32x4 __attribute__((ext_vector_type(4)));
typedef __bf16 bf16x8 __attribute__((ext_vector_type(8)));
typedef u16 u16x8 __attribute__((ext_vector_type(8)));
typedef u16 u16x4 __attribute__((ext_vector_type(4)));

#define S_LEN 1024
#define DMODEL 512
#define NHEAD 8
#define DHEAD 64

__device__ __forceinline__ float bf2f(u16 u) {
    union { unsigned int i; float f; } x; x.i = ((unsigned int)u) << 16; return x.f;
}
__device__ __forceinline__ u16 f2bf(float f) {
    union { float f; unsigned int i; } x; x.f = f;
    unsigned int r = x.i + 0x7fffu + ((x.i >> 16) & 1u);
    return (u16)(r >> 16);
}
__device__ __forceinline__ float load_dual(const void* p, int f32, long idx) {
    return f32 ? ((const float*)p)[idx] : bf2f(((const u16*)p)[idx]);
}

// ---- dtype detector: fp32 mask words are exactly 0.0f or 1.0f ----
__global__ __launch_bounds__(256) void detect_k(const unsigned int* __restrict__ mw,
                                                int* __restrict__ flag) {
    __shared__ int ok;
    int t = threadIdx.x;
    if (t == 0) ok = 1;
    __syncthreads();
    int bad = 0;
    for (int i = t; i < 4096; i += 256) {
        unsigned int w = mw[i];
        if (w != 0u && w != 0x3F800000u) bad = 1;
    }
    if (bad) ok = 0;   // benign race: all writers store 0
    __syncthreads();
    if (t == 0) flag[0] = ok;   // 1 = inputs are fp32, 0 = bf16
}

__global__ void convert_vec_k(const void* __restrict__ in, const int* __restrict__ flag,
                              u16* __restrict__ out, int n) {
    int i = blockIdx.x * 256 + threadIdx.x;
    if (i < n) out[i] = flag[0] ? f2bf(((const float*)in)[i]) : ((const u16*)in)[i];
}

__global__ void transpose_cvt_k(const void* __restrict__ in, const int* __restrict__ flag,
                                u16* __restrict__ out, int R, int C) {
    long idx = (long)blockIdx.x * 256 + threadIdx.x;
    if (idx < (long)R * C) {
        int r = (int)(idx / C), c = (int)(idx % C);
        u16 v = flag[0] ? f2bf(((const float*)in)[idx]) : ((const u16*)in)[idx];
        out[(long)c * R + r] = v;
    }
}

__global__ void convert_x_k(const void* __restrict__ xin, const int* __restrict__ flag,
                            u16* __restrict__ xb, float* __restrict__ xc, int n) {
    int i = blockIdx.x * 256 + threadIdx.x;
    if (i < n) {
        float v = load_dual(xin, flag[0], i);
        xb[i] = f2bf(v);
        xc[i] = v;
    }
}

__global__ __launch_bounds__(256) void count_k(const int* __restrict__ p, float* __restrict__ out) {
    __shared__ int r4[4];
    int t = threadIdx.x;
    int c = 0;
    for (int i = t; i < 1024; i += 256) c += (p[i] != 0) ? 1 : 0;
    for (int off = 32; off; off >>= 1) c += __shfl_xor(c, off);
    if ((t & 63) == 0) r4[t >> 6] = c;
    __syncthreads();
    if (t == 0) out[0] = (float)(r4[0] + r4[1] + r4[2] + r4[3]);
}

enum { M_BF16 = 0, M_BF16_RELU = 1, M_VT = 2, M_F32_RES = 3, M_SMSTAT = 4, M_AW = 5, M_PV = 6 };

// Batched TN GEMM: C[m,n] = sum_k A[m*lda+k] * Bt[n*ldb+k]; z -> (zb=z>>3, zh=z&7).
// 64x64 tile, BK=32, 4 waves, MFMA 16x16x32 bf16 (A[m=lane&15][k=quad*8+j],
// B[n=lane&15][k=quad*8+j], C col=lane&15 row=quad*4+reg).
template <int MODE>
__global__ __launch_bounds__(256) void gemm_tn(
    const u16* __restrict__ A, long sAb, long sAh, int lda,
    const u16* __restrict__ Bt, long sBb, long sBh, int ldb,
    int K,
    const u16* __restrict__ bias,
    void* __restrict__ Cout, int ldc,
    const float* __restrict__ resid,
    const void* __restrict__ maskp,
    float* __restrict__ partials,
    const float* __restrict__ stats,
    void* __restrict__ awout,
    const int* __restrict__ dflag)
{
    __shared__ __align__(16) u16 As[64][40];
    __shared__ __align__(16) u16 Bs[64][40];
    __shared__ float red[8];
    const int tid = threadIdx.x;
    const int wave = tid >> 6, lane = tid & 63;
    const int quad = lane >> 4, l16 = lane & 15;
    const int bm = blockIdx.x * 64, bn = blockIdx.y * 64;
    const int z = blockIdx.z;
    const int zb = z >> 3, zh = z & 7;
    const u16* Ab = A + (long)zb * sAb + (long)zh * sAh;
    const u16* Bb = Bt + (long)zb * sBb + (long)zh * sBh;
    f32x4 acc[4] = {};
    const int lr = tid >> 2;
    const int lc = (tid & 3) << 3;

    for (int k0 = 0; k0 < K; k0 += 32) {
        *(u16x8*)(&As[lr][lc]) = *(const u16x8*)(Ab + (long)(bm + lr) * lda + (k0 + lc));
        *(u16x8*)(&Bs[lr][lc]) = *(const u16x8*)(Bb + (long)(bn + lr) * ldb + (k0 + lc));
        __syncthreads();
        bf16x8 a = *(const bf16x8*)(&As[16 * wave + l16][quad * 8]);
#pragma unroll
        for (int c = 0; c < 4; ++c) {
            bf16x8 b = *(const bf16x8*)(&Bs[16 * c + l16][quad * 8]);
            acc[c] = __builtin_amdgcn_mfma_f32_16x16x32_bf16(a, b, acc[c], 0, 0, 0);
        }
        __syncthreads();
    }

    const int rowb = bm + 16 * wave + quad * 4;

    if constexpr (MODE == M_BF16 || MODE == M_BF16_RELU) {
        u16* Cp = (u16*)Cout;
#pragma unroll
        for (int c = 0; c < 4; ++c) {
            int col = bn + 16 * c + l16;
            float bv = bf2f(bias[col]);
#pragma unroll
            for (int r = 0; r < 4; ++r) {
                float v = acc[c][r] + bv;
                if (MODE == M_BF16_RELU) v = fmaxf(v, 0.0f);
                Cp[(long)(rowb + r) * ldc + col] = f2bf(v);
            }
        }
    } else if constexpr (MODE == M_VT) {
        u16* Cp = (u16*)Cout;
        int b_ = rowb >> 10, ii = rowb & 1023;
#pragma unroll
        for (int c = 0; c < 4; ++c) {
            int col = bn + 16 * c + l16;
            int h = col >> 6, d = col & 63;
            float bv = bf2f(bias[col]);
            u16x4 pk;
#pragma unroll
            for (int r = 0; r < 4; ++r) pk[r] = f2bf(acc[c][r] + bv);
            *(u16x4*)(Cp + ((((long)b_ * NHEAD + h) * DHEAD + d) << 10) + ii) = pk;
        }
    } else if constexpr (MODE == M_F32_RES) {
        float* Cf = (float*)Cout;
#pragma unroll
        for (int c = 0; c < 4; ++c) {
            int col = bn + 16 * c + l16;
            float bv = bf2f(bias[col]);
#pragma unroll
            for (int r = 0; r < 4; ++r) {
                long row = rowb + r;
                Cf[row * ldc + col] = acc[c][r] + bv + resid[row * DMODEL + col];
            }
        }
    } else if constexpr (MODE == M_SMSTAT) {
        const int f32m = dflag[0];
        float vals[16];
        float lm = -3.0e38f;
#pragma unroll
        for (int c = 0; c < 4; ++c) {
            int col = bn + 16 * c + l16;
#pragma unroll
            for (int r = 0; r < 4; ++r) {
                int row = rowb + r;
                float mv = load_dual(maskp, f32m, (long)zb * S_LEN * S_LEN + (long)row * S_LEN + col);
                float lg = (acc[c][r] + mv * (-1e9f)) * 0.125f;
                vals[c * 4 + r] = lg;
                lm = fmaxf(lm, lg);
            }
        }
        for (int off = 32; off; off >>= 1) lm = fmaxf(lm, __shfl_xor(lm, off));
        if (lane == 0) red[wave] = lm;
        __syncthreads();
        float bmax = fmaxf(fmaxf(red[0], red[1]), fmaxf(red[2], red[3]));
        float ls = 0.0f;
#pragma unroll
        for (int i = 0; i < 16; ++i) ls += __expf(fminf(vals[i] - bmax, 0.0f));
        for (int off = 32; off; off >>= 1) ls += __shfl_xor(ls, off);
        if (lane == 0) red[4 + wave] = ls;
        __syncthreads();
        if (tid == 0) {
            int pidx = z * 256 + blockIdx.y * 16 + blockIdx.x;
            partials[2 * pidx] = bmax;
            partials[2 * pidx + 1] = red[4] + red[5] + red[6] + red[7];
        }
    } else if constexpr (MODE == M_AW) {
        const int f32m = dflag[0];
        float Mv = stats[2 * z], sc = stats[2 * z + 1];
        u16* awTz = (u16*)Cout + (long)z * S_LEN * S_LEN;
#pragma unroll
        for (int c = 0; c < 4; ++c) {
            int col = bn + 16 * c + l16;
            u16x4 pk;
#pragma unroll
            for (int r = 0; r < 4; ++r) {
                int row = rowb + r;
                float mv = load_dual(maskp, f32m, (long)zb * S_LEN * S_LEN + (long)row * S_LEN + col);
                float lg = (acc[c][r] + mv * (-1e9f)) * 0.125f;
                float aw = __expf(fminf(lg - Mv, 0.0f)) * sc;
                pk[r] = f2bf(aw);
                if (awout) {
                    long oidx = 2097152 + (long)z * S_LEN * S_LEN + (long)row * S_LEN + col;
                    if (f32m) ((float*)awout)[oidx] = aw;
                    else      ((u16*)awout)[oidx] = pk[r];
                }
            }
            *(u16x4*)(awTz + (long)col * S_LEN + rowb) = pk;
        }
    } else if constexpr (MODE == M_PV) {
        u16* Cp = (u16*)Cout;
        long base = ((long)zb * S_LEN) * DMODEL + zh * DHEAD;
#pragma unroll
        for (int c = 0; c < 4; ++c) {
            int col = 16 * c + l16;
#pragma unroll
            for (int r = 0; r < 4; ++r) {
                Cp[base + (long)(rowb + r) * DMODEL + col] = f2bf(acc[c][r]);
            }
        }
    }
}

__global__ __launch_bounds__(64) void softmax_merge(const float* __restrict__ partials,
                                                    float* __restrict__ stats,
                                                    const float* __restrict__ rowc) {
    int z = blockIdx.x, t = threadIdx.x;
    float lm = -3.0e38f;
    for (int i = t; i < 256; i += 64) lm = fmaxf(lm, partials[2 * (z * 256 + i)]);
    for (int off = 32; off; off >>= 1) lm = fmaxf(lm, __shfl_xor(lm, off));
    float ls = 0.0f;
    for (int i = t; i < 256; i += 64) {
        float m = partials[2 * (z * 256 + i)];
        float s = partials[2 * (z * 256 + i) + 1];
        ls += s * __expf(fminf(m - lm, 0.0f));
    }
    for (int off = 32; off; off >>= 1) ls += __shfl_xor(ls, off);
    if (t == 0) {
        stats[2 * z] = lm;
        stats[2 * z + 1] = rowc[0] / fmaxf(ls, 1e-37f);
    }
}

__global__ __launch_bounds__(256) void layernorm_k(const float* __restrict__ in,
                                                   const u16* __restrict__ g,
                                                   const u16* __restrict__ bb,
                                                   float* __restrict__ outf,
                                                   void* __restrict__ outb,
                                                   const int* __restrict__ of) {
    __shared__ float red[8];
    int row = blockIdx.x, t = threadIdx.x, wave = t >> 6, lane = t & 63;
    const float* x = in + (long)row * DMODEL;
    float v0 = x[t], v1 = x[t + 256];
    float s = v0 + v1;
    for (int off = 32; off; off >>= 1) s += __shfl_xor(s, off);
    if (lane == 0) red[wave] = s;
    __syncthreads();
    float mean = (red[0] + red[1] + red[2] + red[3]) * (1.0f / 512.0f);
    float d0 = v0 - mean, d1 = v1 - mean;
    float q = d0 * d0 + d1 * d1;
    for (int off = 32; off; off >>= 1) q += __shfl_xor(q, off);
    if (lane == 0) red[4 + wave] = q;
    __syncthreads();
    float var = (red[4] + red[5] + red[6] + red[7]) * (1.0f / 512.0f);
    float inv = rsqrtf(var + 1e-9f);
    float o0 = bf2f(g[t]) * d0 * inv + bf2f(bb[t]);
    float o1 = bf2f(g[t + 256]) * d1 * inv + bf2f(bb[t + 256]);
    long base = (long)row * DMODEL;
    if (outf) { outf[base + t] = o0; outf[base + t + 256] = o1; }
    if (of && of[0]) {
        ((float*)outb)[base + t] = o0;
        ((float*)outb)[base + t + 256] = o1;
    } else {
        ((u16*)outb)[base + t] = f2bf(o0);
        ((u16*)outb)[base + t + 256] = f2bf(o1);
    }
}

extern "C" void kernel_launch(void* const* d_in, const int* in_sizes, int n_in,
                              void* d_out, int out_size, void* d_ws, size_t ws_size,
                              hipStream_t stream) {
    const void* x_in   = d_in[0];
    const void* maskr  = d_in[1];
    const int*  protok = (const int*)d_in[2];
    const void* wq_w = d_in[3];  const void* wq_b = d_in[4];
    const void* wk_w = d_in[5];  const void* wk_b = d_in[6];
    const void* wv_w = d_in[7];  const void* wv_b = d_in[8];
    const void* wo_w = d_in[9];  const void* wo_b = d_in[10];
    const void* w1   = d_in[11]; const void* b1   = d_in[12];
    const void* w2   = d_in[13]; const void* b2   = d_in[14];
    const void* ln1g = d_in[15]; const void* ln1b = d_in[16];
    const void* ln2g = d_in[17]; const void* ln2b = d_in[18];

    char* p = (char*)d_ws;
    auto alloc = [&](size_t bytes) { char* r = p; p += (bytes + 255) & ~(size_t)255; return (void*)r; };

    u16* wqT  = (u16*)alloc(512 * 512 * 2);
    u16* wkT  = (u16*)alloc(512 * 512 * 2);
    u16* wvT  = (u16*)alloc(512 * 512 * 2);
    u16* woT  = (u16*)alloc(512 * 512 * 2);
    u16* w1T  = (u16*)alloc((size_t)512 * 2048 * 2);
    u16* w2T  = (u16*)alloc((size_t)2048 * 512 * 2);
    u16* qb   = (u16*)alloc((size_t)4096 * 512 * 2);
    u16* kb   = (u16*)alloc((size_t)4096 * 512 * 2);
    u16* vT   = (u16*)alloc((size_t)32 * 64 * 1024 * 2);
    u16* attn = (u16*)alloc((size_t)4096 * 512 * 2);
    u16* awT  = (u16*)alloc((size_t)32 * 1024 * 1024 * 2);
    float* xcur  = (float*)alloc((size_t)4096 * 512 * 4);
    u16*   xbf   = (u16*)alloc((size_t)4096 * 512 * 2);
    float* resb  = (float*)alloc((size_t)4096 * 512 * 4);
    float* out1f = (float*)alloc((size_t)4096 * 512 * 4);
    u16*   out1b = (u16*)alloc((size_t)4096 * 512 * 2);
    u16*   ffnh  = (u16*)alloc((size_t)4096 * 2048 * 2);
    float* partials = (float*)alloc(32 * 256 * 2 * 4);
    float* stats    = (float*)alloc(32 * 2 * 4);
    float* rowc     = (float*)alloc(256);
    u16*   barena   = (u16*)alloc(8192 * 2);
    int*   dflag    = (int*)alloc(256);

    if ((size_t)(p - (char*)d_ws) > ws_size) return;

    detect_k<<<1, 256, 0, stream>>>((const unsigned int*)maskr, dflag);

    transpose_cvt_k<<<1024, 256, 0, stream>>>(wq_w, dflag, wqT, 512, 512);
    transpose_cvt_k<<<1024, 256, 0, stream>>>(wk_w, dflag, wkT, 512, 512);
    transpose_cvt_k<<<1024, 256, 0, stream>>>(wv_w, dflag, wvT, 512, 512);
    transpose_cvt_k<<<1024, 256, 0, stream>>>(wo_w, dflag, woT, 512, 512);
    transpose_cvt_k<<<4096, 256, 0, stream>>>(w1, dflag, w1T, 512, 2048);
    transpose_cvt_k<<<4096, 256, 0, stream>>>(w2, dflag, w2T, 2048, 512);

    convert_vec_k<<<2, 256, 0, stream>>>(wq_b, dflag, barena + 0, 512);
    convert_vec_k<<<2, 256, 0, stream>>>(wk_b, dflag, barena + 512, 512);
    convert_vec_k<<<2, 256, 0, stream>>>(wv_b, dflag, barena + 1024, 512);
    convert_vec_k<<<2, 256, 0, stream>>>(wo_b, dflag, barena + 1536, 512);
    convert_vec_k<<<8, 256, 0, stream>>>(b1, dflag, barena + 2048, 2048);
    convert_vec_k<<<2, 256, 0, stream>>>(b2, dflag, barena + 4096, 512);
    convert_vec_k<<<2, 256, 0, stream>>>(ln1g, dflag, barena + 4608, 512);
    convert_vec_k<<<2, 256, 0, stream>>>(ln1b, dflag, barena + 5120, 512);
    convert_vec_k<<<2, 256, 0, stream>>>(ln2g, dflag, barena + 5632, 512);
    convert_vec_k<<<2, 256, 0, stream>>>(ln2b, dflag, barena + 6144, 512);

    count_k<<<1, 256, 0, stream>>>(protok, rowc);
    convert_x_k<<<8192, 256, 0, stream>>>(x_in, dflag, xbf, xcur, 2097152);

    const long sQA = (long)S_LEN * DMODEL;
    for (int layer = 0; layer < 4; ++layer) {
        gemm_tn<M_BF16><<<dim3(64, 8, 1), 256, 0, stream>>>(
            xbf, 0, 0, 512, wqT, 0, 0, 512, 512, barena + 0, qb, 512,
            nullptr, nullptr, nullptr, nullptr, nullptr, nullptr);
        gemm_tn<M_BF16><<<dim3(64, 8, 1), 256, 0, stream>>>(
            xbf, 0, 0, 512, wkT, 0, 0, 512, 512, barena + 512, kb, 512,
            nullptr, nullptr, nullptr, nullptr, nullptr, nullptr);
        gemm_tn<M_VT><<<dim3(64, 8, 1), 256, 0, stream>>>(
            xbf, 0, 0, 512, wvT, 0, 0, 512, 512, barena + 1024, vT, 0,
            nullptr, nullptr, nullptr, nullptr, nullptr, nullptr);
        gemm_tn<M_SMSTAT><<<dim3(16, 16, 32), 256, 0, stream>>>(
            qb, sQA, 64, 512, kb, sQA, 64, 512, 64,
            nullptr, nullptr, 0, nullptr, maskr, partials, nullptr, nullptr, dflag);
        softmax_merge<<<32, 64, 0, stream>>>(partials, stats, rowc);
        gemm_tn<M_AW><<<dim3(16, 16, 32), 256, 0, stream>>>(
            qb, sQA, 64, 512, kb, sQA, 64, 512, 64,
            nullptr, awT, 0, nullptr, maskr, nullptr, stats,
            (layer == 3) ? d_out : nullptr, dflag);
        gemm_tn<M_PV><<<dim3(16, 1, 32), 256, 0, stream>>>(
            awT, (long)8 * S_LEN * S_LEN, (long)S_LEN * S_LEN, 1024,
            vT, (long)8 * DHEAD * S_LEN, (long)DHEAD * S_LEN, 1024, 1024,
            nullptr, attn, 0, nullptr, nullptr, nullptr, nullptr, nullptr, nullptr);
        gemm_tn<M_F32_RES><<<dim3(64, 8, 1), 256, 0, stream>>>(
            attn, 0, 0, 512, woT, 0, 0, 512, 512, barena + 1536, resb, 512,
            xcur, nullptr, nullptr, nullptr, nullptr, nullptr);
        layernorm_k<<<4096, 256, 0, stream>>>(resb, barena + 4608, barena + 5120,
                                              out1f, out1b, nullptr);
        gemm_tn<M_BF16_RELU><<<dim3(64, 32, 1), 256, 0, stream>>>(
            out1b, 0, 0, 512, w1T, 0, 0, 512, 512, barena + 2048, ffnh, 2048,
            nullptr, nullptr, nullptr, nullptr, nullptr, nullptr);
        gemm_tn<M_F32_RES><<<dim3(64, 8, 1), 256, 0, stream>>>(
            ffnh, 0, 0, 2048, w2T, 0, 0, 2048, 2048, barena + 4096, resb, 512,
            out1f, nullptr, nullptr, nullptr, nullptr, nullptr);
        layernorm_k<<<4096, 256, 0, stream>>>(resb, barena + 5632, barena + 6144,
                                              xcur, (layer == 3) ? d_out : (void*)xbf,
                                              (layer == 3) ? dflag : nullptr);
    }
}

// Round 3
// 983.443 us; speedup vs baseline: 1.0799x; 1.0799x over previous
//
#include <hip/hip_runtime.h>

typedef unsigned short u16;
typedef float f32x4 __attribute__((ext_vector_type(4)));
typedef __bf16 bf16x8 __attribute__((ext_vector_type(8)));
typedef u16 u16x4 __attribute__((ext_vector_type(4)));

#define S_LEN 1024
#define DMODEL 512

__device__ __forceinline__ float bf2f(u16 u) {
    union { unsigned int i; float f; } x; x.i = ((unsigned int)u) << 16; return x.f;
}
__device__ __forceinline__ u16 f2bf(float f) {
    union { float f; unsigned int i; } x; x.f = f;
    unsigned int r = x.i + 0x7fffu + ((x.i >> 16) & 1u);
    return (u16)(r >> 16);
}
__device__ __forceinline__ float load_dual(const void* p, int f32, long idx) {
    return f32 ? ((const float*)p)[idx] : bf2f(((const u16*)p)[idx]);
}
// async global->LDS, 16B per lane; lds base must be wave-uniform (HW adds lane*16)
__device__ __forceinline__ void load16(const u16* g, u16* lds) {
    __builtin_amdgcn_global_load_lds(
        (const __attribute__((address_space(1))) void*)g,
        (__attribute__((address_space(3))) void*)lds, 16, 0, 0);
}

// ---- dtype detector: fp32 mask words are exactly 0.0f or 1.0f ----
__global__ __launch_bounds__(256) void detect_k(const unsigned int* __restrict__ mw,
                                                int* __restrict__ flag) {
    __shared__ int ok;
    int t = threadIdx.x;
    if (t == 0) ok = 1;
    __syncthreads();
    int bad = 0;
    for (int i = t; i < 4096; i += 256) {
        unsigned int w = mw[i];
        if (w != 0u && w != 0x3F800000u) bad = 1;
    }
    if (bad) ok = 0;
    __syncthreads();
    if (t == 0) flag[0] = ok;   // 1 = inputs fp32, 0 = bf16
}

__global__ void convert_vec_k(const void* __restrict__ in, const int* __restrict__ flag,
                              u16* __restrict__ out, int n) {
    int i = blockIdx.x * 256 + threadIdx.x;
    if (i < n) out[i] = flag[0] ? f2bf(((const float*)in)[i]) : ((const u16*)in)[i];
}

__global__ void transpose_cvt_k(const void* __restrict__ in, const int* __restrict__ flag,
                                u16* __restrict__ out, int R, int C) {
    long idx = (long)blockIdx.x * 256 + threadIdx.x;
    if (idx < (long)R * C) {
        int r = (int)(idx / C), c = (int)(idx % C);
        u16 v = flag[0] ? f2bf(((const float*)in)[idx]) : ((const u16*)in)[idx];
        out[(long)c * R + r] = v;
    }
}

__global__ void convert_x_k(const void* __restrict__ xin, const int* __restrict__ flag,
                            u16* __restrict__ xb, float* __restrict__ xc, int n) {
    int i = blockIdx.x * 256 + threadIdx.x;
    if (i < n) {
        float v = load_dual(xin, flag[0], i);
        xb[i] = f2bf(v);
        xc[i] = v;
    }
}

__global__ __launch_bounds__(256) void count_k(const int* __restrict__ p, float* __restrict__ out) {
    __shared__ int r4[4];
    int t = threadIdx.x;
    int c = 0;
    for (int i = t; i < 1024; i += 256) c += (p[i] != 0) ? 1 : 0;
    for (int off = 32; off; off >>= 1) c += __shfl_xor(c, off);
    if ((t & 63) == 0) r4[t >> 6] = c;
    __syncthreads();
    if (t == 0) out[0] = (float)(r4[0] + r4[1] + r4[2] + r4[3]);
}

enum { G_QKV = 0, G_RELU = 1, G_RES = 2, G_EXP = 3 };

// 128x128 tile, BK=32, 4 waves (each owns a 64x64 quadrant, 4x4 MFMA frags),
// global_load_lds dwordx4 staging (m97 structure). TN: C=A*Bt^T, both k-contiguous.
template <int MODE>
__global__ __launch_bounds__(256) void gemm128(
    const u16* __restrict__ A, int lda,
    const u16* __restrict__ Bt, int ldb,
    int K, const u16* __restrict__ bias,
    void* __restrict__ out0, int ldc,
    u16* __restrict__ out1, u16* __restrict__ out2,
    const float* __restrict__ resid,
    const void* __restrict__ maskp,
    float* __restrict__ partials,
    const int* __restrict__ dflag)
{
    __shared__ __align__(16) u16 As[128 * 32];
    __shared__ __align__(16) u16 Bs[128 * 32];
    __shared__ float redp[4];
    const int tid = threadIdx.x, w = tid >> 6, l = tid & 63;
    const int quad = l >> 4, l16 = l & 15;
    const int bm = blockIdx.x * 128, bn = blockIdx.y * 128;
    const u16* Ab = A;
    const u16* Bb = Bt;
    if constexpr (MODE == G_EXP) {
        int z = blockIdx.z, zb = z >> 3, zh = z & 7;
        Ab += (long)zb * 524288 + zh * 64;
        Bb += (long)zb * 524288 + zh * 64;
    }
    const int srow = (w << 4) + (l >> 2), scol = (l & 3) << 3;
    const int mw = (w >> 1) << 6, nw = (w & 1) << 6;
    f32x4 acc[4][4] = {};

    for (int k0 = 0; k0 < K; k0 += 32) {
        load16(Ab + (long)(bm + srow) * lda + (k0 + scol),      As + (w << 9));
        load16(Ab + (long)(bm + 64 + srow) * lda + (k0 + scol), As + 2048 + (w << 9));
        load16(Bb + (long)(bn + srow) * ldb + (k0 + scol),      Bs + (w << 9));
        load16(Bb + (long)(bn + 64 + srow) * ldb + (k0 + scol), Bs + 2048 + (w << 9));
        __syncthreads();
        bf16x8 a[4], b[4];
#pragma unroll
        for (int i = 0; i < 4; ++i) {
            a[i] = *(const bf16x8*)(As + (mw + (i << 4) + l16) * 32 + (quad << 3));
            b[i] = *(const bf16x8*)(Bs + (nw + (i << 4) + l16) * 32 + (quad << 3));
        }
#pragma unroll
        for (int mi = 0; mi < 4; ++mi)
#pragma unroll
            for (int ni = 0; ni < 4; ++ni)
                acc[mi][ni] = __builtin_amdgcn_mfma_f32_16x16x32_bf16(a[mi], b[ni], acc[mi][ni], 0, 0, 0);
        __syncthreads();
    }

    if constexpr (MODE == G_QKV) {
        u16* qb = (u16*)out0;
#pragma unroll
        for (int ni = 0; ni < 4; ++ni) {
            int col = bn + nw + (ni << 4) + l16;
            float bv = bf2f(bias[col]);
            if (col < 1024) {
                u16* dst = (col < 512) ? qb : out1;
                int cc = col & 511;
#pragma unroll
                for (int mi = 0; mi < 4; ++mi) {
                    int rowb = bm + mw + (mi << 4) + (quad << 2);
#pragma unroll
                    for (int r = 0; r < 4; ++r)
                        dst[(long)(rowb + r) * 512 + cc] = f2bf(acc[mi][ni][r] + bv);
                }
            } else {
                int h = (col - 1024) >> 6, d = col & 63;
#pragma unroll
                for (int mi = 0; mi < 4; ++mi) {
                    int rowb = bm + mw + (mi << 4) + (quad << 2);
                    int b_ = rowb >> 10, ii = rowb & 1023;
                    u16x4 pk;
#pragma unroll
                    for (int r = 0; r < 4; ++r) pk[r] = f2bf(acc[mi][ni][r] + bv);
                    *(u16x4*)(out2 + ((((long)b_ * 8 + h) * 64 + d) << 10) + ii) = pk;
                }
            }
        }
    } else if constexpr (MODE == G_RELU) {
        u16* o = (u16*)out0;
#pragma unroll
        for (int ni = 0; ni < 4; ++ni) {
            int col = bn + nw + (ni << 4) + l16;
            float bv = bf2f(bias[col]);
#pragma unroll
            for (int mi = 0; mi < 4; ++mi) {
                int rowb = bm + mw + (mi << 4) + (quad << 2);
#pragma unroll
                for (int r = 0; r < 4; ++r)
                    o[(long)(rowb + r) * ldc + col] = f2bf(fmaxf(acc[mi][ni][r] + bv, 0.0f));
            }
        }
    } else if constexpr (MODE == G_RES) {
        float* o = (float*)out0;
#pragma unroll
        for (int ni = 0; ni < 4; ++ni) {
            int col = bn + nw + (ni << 4) + l16;
            float bv = bf2f(bias[col]);
#pragma unroll
            for (int mi = 0; mi < 4; ++mi) {
                int rowb = bm + mw + (mi << 4) + (quad << 2);
#pragma unroll
                for (int r = 0; r < 4; ++r) {
                    long row = rowb + r;
                    o[row * ldc + col] = acc[mi][ni][r] + bv + resid[row * DMODEL + col];
                }
            }
        }
    } else if constexpr (MODE == G_EXP) {
        int z = blockIdx.z, zb = z >> 3;
        const int f32m = dflag[0];
        u16* awT = (u16*)out0 + (long)z * 1048576;
        float lsum = 0.0f;
#pragma unroll
        for (int ni = 0; ni < 4; ++ni) {
            int col = bn + nw + (ni << 4) + l16;
#pragma unroll
            for (int mi = 0; mi < 4; ++mi) {
                int rowb = bm + mw + (mi << 4) + (quad << 2);
                u16x4 pk;
#pragma unroll
                for (int r = 0; r < 4; ++r) {
                    int row = rowb + r;
                    float mv = load_dual(maskp, f32m, (long)zb * 1048576 + (long)row * S_LEN + col);
                    float e = __expf((acc[mi][ni][r] + mv * (-1e9f)) * 0.125f);
                    lsum += e;
                    pk[r] = f2bf(e);
                }
                *(u16x4*)(awT + (long)col * S_LEN + rowb) = pk;
            }
        }
        for (int off = 32; off; off >>= 1) lsum += __shfl_xor(lsum, off);
        if (l == 0) redp[w] = lsum;
        __syncthreads();
        if (tid == 0)
            partials[z * 64 + blockIdx.y * 8 + blockIdx.x] =
                redp[0] + redp[1] + redp[2] + redp[3];
    }
}

// PV: out[j,d] = sc * sum_i awT[j,i]*vT[d,i]; 64x64 tile, lds-async staging.
__global__ __launch_bounds__(256) void gemm_pv(const u16* __restrict__ awT,
                                               const u16* __restrict__ vT,
                                               const float* __restrict__ stats,
                                               u16* __restrict__ attn)
{
    __shared__ __align__(16) u16 As[64 * 32];
    __shared__ __align__(16) u16 Bs[64 * 32];
    const int tid = threadIdx.x, w = tid >> 6, l = tid & 63;
    const int quad = l >> 4, l16 = l & 15;
    const int bm = blockIdx.x * 64;
    const int z = blockIdx.y, zb = z >> 3, zh = z & 7;
    const u16* Ab = awT + (long)z * 1048576;
    const u16* Bb = vT + (long)z * 65536;
    const int srow = (w << 4) + (l >> 2), scol = (l & 3) << 3;
    f32x4 acc[4] = {};
    for (int k0 = 0; k0 < 1024; k0 += 32) {
        load16(Ab + (long)(bm + srow) * 1024 + (k0 + scol), As + (w << 9));
        load16(Bb + (long)srow * 1024 + (k0 + scol),        Bs + (w << 9));
        __syncthreads();
        bf16x8 a = *(const bf16x8*)(As + ((w << 4) + l16) * 32 + (quad << 3));
#pragma unroll
        for (int c = 0; c < 4; ++c) {
            bf16x8 b = *(const bf16x8*)(Bs + ((c << 4) + l16) * 32 + (quad << 3));
            acc[c] = __builtin_amdgcn_mfma_f32_16x16x32_bf16(a, b, acc[c], 0, 0, 0);
        }
        __syncthreads();
    }
    float sc = stats[z];
    int rowb = bm + (w << 4) + (quad << 2);
    long base = (long)zb * 524288 + (long)zh * 64;
#pragma unroll
    for (int c = 0; c < 4; ++c) {
        int col = (c << 4) + l16;
#pragma unroll
        for (int r = 0; r < 4; ++r)
            attn[base + (long)(rowb + r) * 512 + col] = f2bf(acc[c][r] * sc);
    }
}

__global__ __launch_bounds__(64) void softmax_merge(const float* __restrict__ partials,
                                                    float* __restrict__ stats,
                                                    const float* __restrict__ rowc) {
    int z = blockIdx.x, t = threadIdx.x;
    float s = partials[z * 64 + t];
    for (int off = 32; off; off >>= 1) s += __shfl_xor(s, off);
    if (t == 0) stats[z] = rowc[0] / fmaxf(s, 1e-30f);
}

// final aw output: aw[z][i][j] = awT[z][j][i] * sc[z], 32x32 LDS tiles
__global__ __launch_bounds__(256) void aw_norm_k(const u16* __restrict__ awT,
                                                 const float* __restrict__ stats,
                                                 void* __restrict__ dout,
                                                 const int* __restrict__ dflag) {
    __shared__ u16 t[32][33];
    int z = blockIdx.z;
    float sc = stats[z];
    int i0 = blockIdx.x << 5, j0 = blockIdx.y << 5;
    int tx = threadIdx.x & 31, ty = threadIdx.x >> 5;   // ty 0..7
    const u16* src = awT + (long)z * 1048576;
#pragma unroll
    for (int r = 0; r < 4; ++r) {
        int j = j0 + ty + (r << 3);
        t[ty + (r << 3)][tx] = src[(long)j * 1024 + i0 + tx];
    }
    __syncthreads();
    long obase = 2097152 + (long)z * 1048576;
    int f32o = dflag[0];
#pragma unroll
    for (int r = 0; r < 4; ++r) {
        int i = i0 + ty + (r << 3);
        float v = bf2f(t[tx][ty + (r << 3)]) * sc;
        long oi = obase + (long)i * 1024 + j0 + tx;
        if (f32o) ((float*)dout)[oi] = v;
        else      ((u16*)dout)[oi] = f2bf(v);
    }
}

__global__ __launch_bounds__(256) void layernorm_k(const float* __restrict__ in,
                                                   const u16* __restrict__ g,
                                                   const u16* __restrict__ bb,
                                                   float* __restrict__ outf,
                                                   void* __restrict__ outb,
                                                   const int* __restrict__ of) {
    __shared__ float red[8];
    int row = blockIdx.x, t = threadIdx.x, wave = t >> 6, lane = t & 63;
    const float* x = in + (long)row * DMODEL;
    float v0 = x[t], v1 = x[t + 256];
    float s = v0 + v1;
    for (int off = 32; off; off >>= 1) s += __shfl_xor(s, off);
    if (lane == 0) red[wave] = s;
    __syncthreads();
    float mean = (red[0] + red[1] + red[2] + red[3]) * (1.0f / 512.0f);
    float d0 = v0 - mean, d1 = v1 - mean;
    float q = d0 * d0 + d1 * d1;
    for (int off = 32; off; off >>= 1) q += __shfl_xor(q, off);
    if (lane == 0) red[4 + wave] = q;
    __syncthreads();
    float var = (red[4] + red[5] + red[6] + red[7]) * (1.0f / 512.0f);
    float inv = rsqrtf(var + 1e-9f);
    float o0 = bf2f(g[t]) * d0 * inv + bf2f(bb[t]);
    float o1 = bf2f(g[t + 256]) * d1 * inv + bf2f(bb[t + 256]);
    long base = (long)row * DMODEL;
    if (outf) { outf[base + t] = o0; outf[base + t + 256] = o1; }
    if (of && of[0]) {
        ((float*)outb)[base + t] = o0;
        ((float*)outb)[base + t + 256] = o1;
    } else {
        ((u16*)outb)[base + t] = f2bf(o0);
        ((u16*)outb)[base + t + 256] = f2bf(o1);
    }
}

extern "C" void kernel_launch(void* const* d_in, const int* in_sizes, int n_in,
                              void* d_out, int out_size, void* d_ws, size_t ws_size,
                              hipStream_t stream) {
    const void* x_in   = d_in[0];
    const void* maskr  = d_in[1];
    const int*  protok = (const int*)d_in[2];
    const void* wq_w = d_in[3];  const void* wq_b = d_in[4];
    const void* wk_w = d_in[5];  const void* wk_b = d_in[6];
    const void* wv_w = d_in[7];  const void* wv_b = d_in[8];
    const void* wo_w = d_in[9];  const void* wo_b = d_in[10];
    const void* w1   = d_in[11]; const void* b1   = d_in[12];
    const void* w2   = d_in[13]; const void* b2   = d_in[14];
    const void* ln1g = d_in[15]; const void* ln1b = d_in[16];
    const void* ln2g = d_in[17]; const void* ln2b = d_in[18];

    char* p = (char*)d_ws;
    auto alloc = [&](size_t bytes) { char* r = p; p += (bytes + 255) & ~(size_t)255; return (void*)r; };

    u16* wqkvT = (u16*)alloc((size_t)1536 * 512 * 2);
    u16* woT   = (u16*)alloc(512 * 512 * 2);
    u16* w1T   = (u16*)alloc((size_t)512 * 2048 * 2);
    u16* w2T   = (u16*)alloc((size_t)2048 * 512 * 2);
    u16* qb    = (u16*)alloc((size_t)4096 * 512 * 2);
    u16* kb    = (u16*)alloc((size_t)4096 * 512 * 2);
    u16* vT    = (u16*)alloc((size_t)32 * 64 * 1024 * 2);
    u16* attn  = (u16*)alloc((size_t)4096 * 512 * 2);
    u16* awT   = (u16*)alloc((size_t)32 * 1024 * 1024 * 2);
    float* xcur  = (float*)alloc((size_t)4096 * 512 * 4);
    u16*   xbf   = (u16*)alloc((size_t)4096 * 512 * 2);
    float* resb  = (float*)alloc((size_t)4096 * 512 * 4);
    float* out1f = (float*)alloc((size_t)4096 * 512 * 4);
    u16*   out1b = (u16*)alloc((size_t)4096 * 512 * 2);
    u16*   ffnh  = (u16*)alloc((size_t)4096 * 2048 * 2);
    float* partials = (float*)alloc(32 * 64 * 4);
    float* stats    = (float*)alloc(32 * 4);
    float* rowc     = (float*)alloc(256);
    u16*   barena   = (u16*)alloc(8192 * 2);
    int*   dflag    = (int*)alloc(256);

    if ((size_t)(p - (char*)d_ws) > ws_size) return;

    detect_k<<<1, 256, 0, stream>>>((const unsigned int*)maskr, dflag);

    transpose_cvt_k<<<1024, 256, 0, stream>>>(wq_w, dflag, wqkvT, 512, 512);
    transpose_cvt_k<<<1024, 256, 0, stream>>>(wk_w, dflag, wqkvT + 512 * 512, 512, 512);
    transpose_cvt_k<<<1024, 256, 0, stream>>>(wv_w, dflag, wqkvT + 1024 * 512, 512, 512);
    transpose_cvt_k<<<1024, 256, 0, stream>>>(wo_w, dflag, woT, 512, 512);
    transpose_cvt_k<<<4096, 256, 0, stream>>>(w1, dflag, w1T, 512, 2048);
    transpose_cvt_k<<<4096, 256, 0, stream>>>(w2, dflag, w2T, 2048, 512);

    convert_vec_k<<<2, 256, 0, stream>>>(wq_b, dflag, barena + 0, 512);
    convert_vec_k<<<2, 256, 0, stream>>>(wk_b, dflag, barena + 512, 512);
    convert_vec_k<<<2, 256, 0, stream>>>(wv_b, dflag, barena + 1024, 512);
    convert_vec_k<<<2, 256, 0, stream>>>(wo_b, dflag, barena + 1536, 512);
    convert_vec_k<<<8, 256, 0, stream>>>(b1, dflag, barena + 2048, 2048);
    convert_vec_k<<<2, 256, 0, stream>>>(b2, dflag, barena + 4096, 512);
    convert_vec_k<<<2, 256, 0, stream>>>(ln1g, dflag, barena + 4608, 512);
    convert_vec_k<<<2, 256, 0, stream>>>(ln1b, dflag, barena + 5120, 512);
    convert_vec_k<<<2, 256, 0, stream>>>(ln2g, dflag, barena + 5632, 512);
    convert_vec_k<<<2, 256, 0, stream>>>(ln2b, dflag, barena + 6144, 512);

    count_k<<<1, 256, 0, stream>>>(protok, rowc);
    convert_x_k<<<8192, 256, 0, stream>>>(x_in, dflag, xbf, xcur, 2097152);

    for (int layer = 0; layer < 4; ++layer) {
        // fused QKV projection: N=1536
        gemm128<G_QKV><<<dim3(32, 12, 1), 256, 0, stream>>>(
            xbf, 512, wqkvT, 512, 512, barena + 0,
            qb, 512, kb, vT, nullptr, nullptr, nullptr, nullptr);
        // logits + exp + partial sums (single pass, no max subtraction)
        gemm128<G_EXP><<<dim3(8, 8, 32), 256, 0, stream>>>(
            qb, 512, kb, 512, 64, nullptr,
            awT, 0, nullptr, nullptr, nullptr, maskr, partials, dflag);
        softmax_merge<<<32, 64, 0, stream>>>(partials, stats, rowc);
        if (layer == 3)
            aw_norm_k<<<dim3(32, 32, 32), 256, 0, stream>>>(awT, stats, d_out, dflag);
        // PV with normalization scale folded in
        gemm_pv<<<dim3(16, 32), 256, 0, stream>>>(awT, vT, stats, attn);
        // Wo + bias + residual
        gemm128<G_RES><<<dim3(32, 4, 1), 256, 0, stream>>>(
            attn, 512, woT, 512, 512, barena + 1536,
            resb, 512, nullptr, nullptr, xcur, nullptr, nullptr, nullptr);
        layernorm_k<<<4096, 256, 0, stream>>>(resb, barena + 4608, barena + 5120,
                                              out1f, out1b, nullptr);
        // FFN
        gemm128<G_RELU><<<dim3(32, 16, 1), 256, 0, stream>>>(
            out1b, 512, w1T, 512, 512, barena + 2048,
            ffnh, 2048, nullptr, nullptr, nullptr, nullptr, nullptr, nullptr);
        gemm128<G_RES><<<dim3(32, 4, 1), 256, 0, stream>>>(
            ffnh, 2048, w2T, 2048, 2048, barena + 4096,
            resb, 512, nullptr, nullptr, out1f, nullptr, nullptr, nullptr);
        layernorm_k<<<4096, 256, 0, stream>>>(resb, barena + 5632, barena + 6144,
                                              xcur, (layer == 3) ? d_out : (void*)xbf,
                                              (layer == 3) ? dflag : nullptr);
    }
}